// Round 1
// baseline (616.997 us; speedup 1.0000x reference)
//
#include <hip/hip_runtime.h>
#include <stdint.h>

typedef unsigned short u16;
typedef unsigned int u32;

#define S_LEN 4096
#define EMB 2048
#define NH 16
#define HD 128
#define HDTOT 2048
#define T_TILES 32
#define KANCH 8
#define SM_SCALE 0.088388347648318447f

typedef __bf16 bf16x8 __attribute__((ext_vector_type(8)));
typedef float f32x4 __attribute__((ext_vector_type(4)));

typedef const __attribute__((address_space(1))) u32 ga_u32;
typedef __attribute__((address_space(3))) u32 lds_u32;

__device__ __forceinline__ u16 f2bf(float f) {
  u32 b = __builtin_bit_cast(u32, f);
  b = (b + 0x7FFFu + ((b >> 16) & 1u)) >> 16;
  return (u16)b;
}
__device__ __forceinline__ float bf2f(u16 u) {
  return __builtin_bit_cast(float, ((u32)u) << 16);
}
__device__ __forceinline__ f32x4 mfma16(bf16x8 a, bf16x8 b, f32x4 c) {
  return __builtin_amdgcn_mfma_f32_16x16x32_bf16(a, b, c, 0, 0, 0);
}

// ---------------- x: fp32 -> bf16 ----------------
__global__ __launch_bounds__(256) void k_convert_x(const float* __restrict__ x,
                                                   u16* __restrict__ xb) {
  int i = (blockIdx.x * 256 + threadIdx.x) * 4;
  float4 v = *(const float4*)(x + i);
  ushort4 o;
  o.x = f2bf(v.x); o.y = f2bf(v.y); o.z = f2bf(v.z); o.w = f2bf(v.w);
  *(ushort4*)(xb + i) = o;
}

// ------- weights: [K=2048][N=2048] fp32 -> [N][K] bf16 (B^T for gemm) -------
__global__ __launch_bounds__(256) void k_transpose_w(
    const float* __restrict__ w0, const float* __restrict__ w1,
    const float* __restrict__ w2, const float* __restrict__ w3,
    u16* __restrict__ o0, u16* __restrict__ o1,
    u16* __restrict__ o2, u16* __restrict__ o3) {
  const float* w; u16* o;
  if (blockIdx.z == 0)      { w = w0; o = o0; }
  else if (blockIdx.z == 1) { w = w1; o = o1; }
  else if (blockIdx.z == 2) { w = w2; o = o2; }
  else                      { w = w3; o = o3; }
  __shared__ float tile[64][68];
  int n0 = blockIdx.x * 64, k0 = blockIdx.y * 64;
  int tid = threadIdx.x;
  int r = tid >> 4, cq = (tid & 15) << 2;
  for (int p = 0; p < 4; ++p) {
    float4 v = *(const float4*)(w + (size_t)(k0 + r + p * 16) * EMB + n0 + cq);
    tile[r + p * 16][cq + 0] = v.x;
    tile[r + p * 16][cq + 1] = v.y;
    tile[r + p * 16][cq + 2] = v.z;
    tile[r + p * 16][cq + 3] = v.w;
  }
  __syncthreads();
  for (int p = 0; p < 4; ++p) {
    int rn = r + p * 16;
    ushort4 u;
    u.x = f2bf(tile[cq + 0][rn]);
    u.y = f2bf(tile[cq + 1][rn]);
    u.z = f2bf(tile[cq + 2][rn]);
    u.w = f2bf(tile[cq + 3][rn]);
    *(ushort4*)(o + (size_t)(n0 + rn) * EMB + k0 + cq) = u;
  }
}

// ------- v: [S][HDTOT] bf16 -> vT [HDTOT][S] bf16 -------
__global__ __launch_bounds__(256) void k_transpose_v(const u16* __restrict__ v,
                                                     u16* __restrict__ vt) {
  __shared__ u16 tile[64][72];
  int n0 = blockIdx.x * 64, s0 = blockIdx.y * 64;
  int tid = threadIdx.x;
  int r = tid >> 4, cq = (tid & 15) << 2;
  for (int p = 0; p < 4; ++p) {
    ushort4 u = *(const ushort4*)(v + (size_t)(s0 + r + p * 16) * HDTOT + n0 + cq);
    tile[r + p * 16][cq + 0] = u.x;
    tile[r + p * 16][cq + 1] = u.y;
    tile[r + p * 16][cq + 2] = u.z;
    tile[r + p * 16][cq + 3] = u.w;
  }
  __syncthreads();
  for (int p = 0; p < 4; ++p) {
    int rn = r + p * 16;
    ushort4 o;
    o.x = tile[cq + 0][rn];
    o.y = tile[cq + 1][rn];
    o.z = tile[cq + 2][rn];
    o.w = tile[cq + 3][rn];
    *(ushort4*)(vt + (size_t)(n0 + rn) * S_LEN + s0 + cq) = o;
  }
}

// ------- m97-style bf16 GEMM: C[M][N] = A[M][K] * Bt[N][K]^T -------
template <bool BF16OUT>
__global__ __launch_bounds__(256) void k_gemm(const u16* __restrict__ A,
                                              const u16* __restrict__ Bt,
                                              void* __restrict__ Cv,
                                              int M, int N, int K) {
  __shared__ __align__(16) u16 As[128 * 32];
  __shared__ __align__(16) u16 Bs[128 * 32];
  const int tid = threadIdx.x;
  const int lane = tid & 63, wave = tid >> 6;
  const int quad = lane >> 4, l16 = lane & 15;
  const int m0 = blockIdx.y * 128, n0 = blockIdx.x * 128;
  const int wm = (wave >> 1) * 64, wn = (wave & 1) * 64;
  f32x4 acc[4][4] = {};

  const int flat0 = wave * 1024 + lane * 16;  // byte offset within 8KB tile
  for (int kt = 0; kt < K; kt += 32) {
    for (int half = 0; half < 2; ++half) {
      int flat = flat0 + half * 4096;
      int row = flat >> 6, colb = flat & 63;
      const char* ga = (const char*)A + ((size_t)(m0 + row) * K + kt) * 2 + colb;
      const char* gb = (const char*)Bt + ((size_t)(n0 + row) * K + kt) * 2 + colb;
      int loff = wave * 1024 + half * 4096;  // wave-uniform LDS byte offset
      __builtin_amdgcn_global_load_lds((ga_u32*)ga, (lds_u32*)((char*)As + loff), 16, 0, 0);
      __builtin_amdgcn_global_load_lds((ga_u32*)gb, (lds_u32*)((char*)Bs + loff), 16, 0, 0);
    }
    __syncthreads();
    bf16x8 af[4], bfr[4];
    for (int mt = 0; mt < 4; ++mt)
      af[mt] = *(const bf16x8*)(As + (wm + mt * 16 + l16) * 32 + quad * 8);
    for (int nt = 0; nt < 4; ++nt)
      bfr[nt] = *(const bf16x8*)(Bs + (wn + nt * 16 + l16) * 32 + quad * 8);
    for (int mt = 0; mt < 4; ++mt)
      for (int nt = 0; nt < 4; ++nt)
        acc[mt][nt] = mfma16(af[mt], bfr[nt], acc[mt][nt]);
    __syncthreads();
  }
  for (int mt = 0; mt < 4; ++mt) {
    int row = m0 + wm + mt * 16 + quad * 4;
    for (int nt = 0; nt < 4; ++nt) {
      int col = n0 + wn + nt * 16 + l16;
      for (int r = 0; r < 4; ++r) {
        if (BF16OUT)
          ((u16*)Cv)[(size_t)(row + r) * N + col] = f2bf(acc[mt][nt][r]);
        else
          ((float*)Cv)[(size_t)(row + r) * N + col] = acc[mt][nt][r];
      }
    }
  }
}

// ------- RoPE (half-split) applied in-place to q and k -------
__global__ __launch_bounds__(256) void k_rope(u16* __restrict__ q, u16* __restrict__ k,
                                              const float* __restrict__ ang) {
  int gid = blockIdx.x * 256 + threadIdx.x;  // S*NH*64
  int s = gid >> 10;
  int h = (gid >> 6) & (NH - 1);
  int d = gid & 63;
  float a = ang[s * 64 + d];
  float sn, cs;
  __sincosf(a, &sn, &cs);
  size_t base = (size_t)s * HDTOT + h * HD + d;
  float q1 = bf2f(q[base]), q2 = bf2f(q[base + 64]);
  q[base] = f2bf(q1 * cs - q2 * sn);
  q[base + 64] = f2bf(q2 * cs + q1 * sn);
  float k1 = bf2f(k[base]), k2 = bf2f(k[base + 64]);
  k[base] = f2bf(k1 * cs - k2 * sn);
  k[base + 64] = f2bf(k2 * cs + k1 * sn);
}

// ------- attention helpers: XOR-swizzled 128x128 bf16 LDS tiles -------
__device__ __forceinline__ void stage128(u16* __restrict__ sbuf, const u16* __restrict__ g,
                                         int gpitch, int tid) {
  for (int p = 0; p < 8; ++p) {
    int flat = p * 2048 + tid * 8;
    int r = flat >> 7, c = flat & 127;
    uint4 val = *(const uint4*)(g + (size_t)r * gpitch + c);
    *(uint4*)(sbuf + r * 128 + (((c >> 3) ^ (r & 15)) << 3)) = val;
  }
}
__device__ __forceinline__ bf16x8 ldsfrag(const u16* __restrict__ sbuf, int r, int cb) {
  return *(const bf16x8*)(sbuf + r * 128 + (((cb ^ (r & 15)) << 3)));
}

// ------- block-sparse flash attention: one block per (t, h) -------
__global__ __launch_bounds__(256, 2) void k_attn(const u16* __restrict__ q,
                                                 const u16* __restrict__ k,
                                                 const u16* __restrict__ vt,
                                                 const int* __restrict__ anch,
                                                 u16* __restrict__ out) {
  __shared__ __align__(16) u16 bufK[128 * 128];  // Q -> K_j -> P overlay
  __shared__ __align__(16) u16 bufV[128 * 128];  // V_j^T
  const int t = blockIdx.x, h = blockIdx.y;
  const int tid = threadIdx.x;
  const int lane = tid & 63, wave = tid >> 6;
  const int quad = lane >> 4, l16 = lane & 15;

  // stage Q tile, pull A-frags to registers
  stage128(bufK, q + (size_t)(t * 128) * HDTOT + h * HD, HDTOT, tid);
  __syncthreads();
  bf16x8 qf[2][4];
  for (int mt = 0; mt < 2; ++mt)
    for (int ks = 0; ks < 4; ++ks)
      qf[mt][ks] = ldsfrag(bufK, wave * 32 + mt * 16 + l16, ks * 4 + quad);
  __syncthreads();

  f32x4 oacc[2][8] = {};
  float mrow[2][4], lrow[2][4];
  for (int mt = 0; mt < 2; ++mt)
    for (int r = 0; r < 4; ++r) { mrow[mt][r] = -1e30f; lrow[mt][r] = 0.f; }

  for (int j = 0; j <= KANCH; ++j) {
    int tj = (j < KANCH) ? anch[((h * T_TILES) + t) * KANCH + j] : t;
    if (tj > t) continue;  // fully future-masked: exact zero contribution

    stage128(bufK, k + (size_t)(tj * 128) * HDTOT + h * HD, HDTOT, tid);
    stage128(bufV, vt + (size_t)(h * HD) * S_LEN + tj * 128, S_LEN, tid);
    __syncthreads();

    // S = Q K^T  (wave owns 32 q-rows x 128 keys)
    f32x4 sacc[2][8] = {};
    for (int ks = 0; ks < 4; ++ks)
      for (int nt = 0; nt < 8; ++nt) {
        bf16x8 bk = ldsfrag(bufK, nt * 16 + l16, ks * 4 + quad);
        sacc[0][nt] = mfma16(qf[0][ks], bk, sacc[0][nt]);
        sacc[1][nt] = mfma16(qf[1][ks], bk, sacc[1][nt]);
      }
    __syncthreads();  // all waves done reading K; bufK free for P overlay

    const bool diag = (tj == t);
    for (int mt = 0; mt < 2; ++mt) {
      float rmax[4] = {-1e30f, -1e30f, -1e30f, -1e30f};
      for (int nt = 0; nt < 8; ++nt) {
        f32x4 s4 = sacc[mt][nt];
        for (int r = 0; r < 4; ++r) {
          float sv = s4[r] * SM_SCALE;
          if (diag && (nt * 16 + l16 > wave * 32 + mt * 16 + quad * 4 + r)) sv = -1e30f;
          s4[r] = sv;
          rmax[r] = fmaxf(rmax[r], sv);
        }
        sacc[mt][nt] = s4;
      }
      float alpha[4];
      for (int r = 0; r < 4; ++r) {
        float rm = rmax[r];
        rm = fmaxf(rm, __shfl_xor(rm, 1));
        rm = fmaxf(rm, __shfl_xor(rm, 2));
        rm = fmaxf(rm, __shfl_xor(rm, 4));
        rm = fmaxf(rm, __shfl_xor(rm, 8));
        float mnew = fmaxf(mrow[mt][r], rm);
        alpha[r] = __expf(mrow[mt][r] - mnew);
        mrow[mt][r] = mnew;
      }
      float rsum[4] = {0.f, 0.f, 0.f, 0.f};
      for (int nt = 0; nt < 8; ++nt) {
        f32x4 s4 = sacc[mt][nt];
        for (int r = 0; r < 4; ++r) {
          float p = __expf(s4[r] - mrow[mt][r]);
          s4[r] = p;
          rsum[r] += p;
        }
        sacc[mt][nt] = s4;
      }
      for (int r = 0; r < 4; ++r) {
        float rs = rsum[r];
        rs += __shfl_xor(rs, 1);
        rs += __shfl_xor(rs, 2);
        rs += __shfl_xor(rs, 4);
        rs += __shfl_xor(rs, 8);
        lrow[mt][r] = lrow[mt][r] * alpha[r] + rs;
      }
      // rescale O and write P (bf16) into bufK overlay
      for (int nt = 0; nt < 8; ++nt) {
        f32x4 o4 = oacc[mt][nt];
        f32x4 s4 = sacc[mt][nt];
        for (int r = 0; r < 4; ++r) {
          o4[r] *= alpha[r];
          int qrow = wave * 32 + mt * 16 + quad * 4 + r;
          int c = nt * 16 + l16;
          bufK[qrow * 128 + ((((c >> 3) ^ (qrow & 15)) << 3)) + (c & 7)] = f2bf(s4[r]);
        }
        oacc[mt][nt] = o4;
      }
    }
    __syncthreads();  // P visible in A-layout order

    // O += P V  (A-frags from P overlay, B-frags from V^T)
    for (int ks = 0; ks < 4; ++ks) {
      bf16x8 pa0 = ldsfrag(bufK, wave * 32 + l16, ks * 4 + quad);
      bf16x8 pa1 = ldsfrag(bufK, wave * 32 + 16 + l16, ks * 4 + quad);
      for (int nt = 0; nt < 8; ++nt) {
        bf16x8 bv = ldsfrag(bufV, nt * 16 + l16, ks * 4 + quad);
        oacc[0][nt] = mfma16(pa0, bv, oacc[0][nt]);
        oacc[1][nt] = mfma16(pa1, bv, oacc[1][nt]);
      }
    }
    __syncthreads();  // done reading bufK/bufV before next staging
  }

  for (int mt = 0; mt < 2; ++mt)
    for (int r = 0; r < 4; ++r) {
      float inv = 1.0f / lrow[mt][r];
      size_t srow = (size_t)(t * 128 + wave * 32 + mt * 16 + quad * 4 + r);
      for (int nt = 0; nt < 8; ++nt)
        out[srow * HDTOT + h * HD + nt * 16 + l16] = f2bf(oacc[mt][nt][r] * inv);
    }
}

extern "C" void kernel_launch(void* const* d_in, const int* in_sizes, int n_in,
                              void* d_out, int out_size, void* d_ws, size_t ws_size,
                              hipStream_t stream) {
  const float* x   = (const float*)d_in[0];
  const float* wq  = (const float*)d_in[1];
  const float* wk  = (const float*)d_in[2];
  const float* wv  = (const float*)d_in[3];
  const float* wo  = (const float*)d_in[4];
  const float* ang = (const float*)d_in[5];
  const int* anch  = (const int*)d_in[6];

  char* ws = (char*)d_ws;
  const size_t SZ_SE = (size_t)S_LEN * HDTOT * sizeof(u16);  // 16 MB
  const size_t SZ_W  = (size_t)EMB * EMB * sizeof(u16);      // 8 MB
  u16* xb   = (u16*)(ws);
  u16* qb   = (u16*)(ws + SZ_SE);
  u16* kb   = (u16*)(ws + 2 * SZ_SE);
  u16* vb   = (u16*)(ws + 3 * SZ_SE);
  u16* vtb  = (u16*)(ws + 4 * SZ_SE);
  u16* attn = (u16*)(ws + 5 * SZ_SE);
  u16* wqT  = (u16*)(ws + 6 * SZ_SE);
  u16* wkT  = (u16*)(ws + 6 * SZ_SE + SZ_W);
  u16* wvT  = (u16*)(ws + 6 * SZ_SE + 2 * SZ_W);
  u16* woT  = (u16*)(ws + 6 * SZ_SE + 3 * SZ_W);

  k_convert_x<<<8192, 256, 0, stream>>>(x, xb);
  k_transpose_w<<<dim3(32, 32, 4), 256, 0, stream>>>(wq, wk, wv, wo, wqT, wkT, wvT, woT);
  k_gemm<true><<<dim3(16, 32), 256, 0, stream>>>(xb, wqT, qb, S_LEN, HDTOT, EMB);
  k_gemm<true><<<dim3(16, 32), 256, 0, stream>>>(xb, wkT, kb, S_LEN, HDTOT, EMB);
  k_gemm<true><<<dim3(16, 32), 256, 0, stream>>>(xb, wvT, vb, S_LEN, HDTOT, EMB);
  k_rope<<<16384, 256, 0, stream>>>(qb, kb, ang);
  k_transpose_v<<<dim3(32, 64), 256, 0, stream>>>(vb, vtb);
  k_attn<<<dim3(T_TILES, NH), 256, 0, stream>>>(qb, kb, vtb, anch, attn);
  k_gemm<false><<<dim3(16, 32), 256, 0, stream>>>(attn, woT, d_out, S_LEN, EMB, HDTOT);
}